// Round 10
// baseline (83.216 us; speedup 1.0000x reference)
//
#include <hip/hip_runtime.h>
#include <hip/hip_bf16.h>

// Fused map-obs attention (Attention_5815385719367), MI355X/gfx950.
// R10: occupancy was GRID-capped at 16 waves/CU (1024 blocks x 4 waves =
// 4 blocks/CU). VGPR=60 <= 64 allows 8 waves/SIMD, so: ks 8 -> 16, grid =
// 128*16 = 2048 = 8 blocks/CU x 4 waves = 32 waves/CU (100%). XCD locality
// kept (bid%8 == slice%8 -> 2 slabs = 0.75MB per XCD L2). Prep reverted to
// R8 shape (32 rows/block; R9's 16-row blocks doubled weight re-reads).
//
// ws layout (~24 MB):
//   qbf  [n_map][64] bf16 (pre-scaled by IT)
//   Kp   [n_obs/32][4][64][8] bf16    (packed K fragments)
//   Vp   [n_obs/32][2][64][8] bf16    (packed V^T fragments)
//   self_score[n_map] f32, gated_map[n_map][32] f32
//   oP [ks][ntiles][32][32] bf16,  lP [ks][n_map] f32

typedef float f32x16 __attribute__((ext_vector_type(16)));
typedef short bf16x8 __attribute__((ext_vector_type(8)));
typedef unsigned int u32;

__device__ __forceinline__ u32 cvt_pk_bf16(float lo, float hi) {
    u32 r;
    asm("v_cvt_pk_bf16_f32 %0, %1, %2" : "=v"(r) : "v"(lo), "v"(hi));
    return r;
}
__device__ __forceinline__ void permswap32(u32& a, u32& b) {
    asm("v_permlane32_swap_b32 %0, %1" : "+v"(a), "+v"(b));
}

#define IT 0.18033688011112042f  // log2(e)/TEMPERATURE, T=8
#define LOG2E 1.44269504089f

// ---------------------------------------------------------------- prep ----
// 256 thr = 4 waves; wave handles 8 rows (32 rows/block), d-loop outer.
__global__ __launch_bounds__(256) void prep_kernel(
    const float* __restrict__ map_code, const float* __restrict__ obs_code,
    const float* __restrict__ Wq, const float* __restrict__ Wk,
    const float* __restrict__ Wv,
    __hip_bfloat16* __restrict__ qbf, __hip_bfloat16* __restrict__ Kp,
    __hip_bfloat16* __restrict__ Vp, float* __restrict__ self_score,
    float* __restrict__ gated_map, int n_map, int n_obs)
{
    __shared__ float xs[32 * 64];
    const int t = threadIdx.x;
    const int w = t >> 6;
    const int e = t & 63;
    const int r0 = blockIdx.x * 32;
    const int total = n_map + n_obs;

    // stage 32 rows of concat(map, obs), coalesced
    #pragma unroll
    for (int i = 0; i < 8; ++i) {
        const int idx = i * 256 + t;
        const int gr = r0 + (idx >> 6);
        const int col = idx & 63;
        float val = 0.0f;
        if (gr < n_map)      val = map_code[(size_t)gr * 64 + col];
        else if (gr < total) val = obs_code[(size_t)(gr - n_map) * 64 + col];
        xs[idx] = val;
    }
    __syncthreads();

    float qa[8] = {}, ka[8] = {}, va[8] = {};
    const float* xw = xs + (w * 8) * 64;
    #pragma unroll 4
    for (int d = 0; d < 64; ++d) {
        const float wq = Wq[d * 64 + e];
        const float wk = Wk[d * 64 + e];
        const float wv = Wv[d * 64 + e];
        #pragma unroll
        for (int i = 0; i < 8; ++i) {
            const float x = xw[i * 64 + d];   // LDS broadcast
            qa[i] = fmaf(x, wq, qa[i]);
            ka[i] = fmaf(x, wk, ka[i]);
            va[i] = fmaf(x, wv, va[i]);
        }
    }

    #pragma unroll
    for (int i = 0; i < 8; ++i) {
        const int r = r0 + w * 8 + i;
        if (r >= total) break;
        const bool is_map = r < n_map;
        // GLU: lanes 0..31 hold a=v[e], need b=v[e+32]
        const float vother = __shfl_xor(va[i], 32);
        const float sig = 1.0f / (1.0f + __builtin_amdgcn_exp2f(-vother * LOG2E));
        const float g = va[i] * sig; // valid for lanes e < 32

        if (is_map) {
            qbf[(size_t)r * 64 + e] = __float2bfloat16(qa[i] * IT);
            float qk = qa[i] * ka[i];
            #pragma unroll
            for (int off = 32; off; off >>= 1) qk += __shfl_xor(qk, off);
            if (e == 0) self_score[r] = qk;
            if (e < 32) gated_map[(size_t)r * 32 + e] = g;
        } else {
            const int j  = r - n_map;          // key index
            const int kb = j >> 5, jq = j & 31;
            {   // Kp: thread e holds K[j][d=e]
                const int c = e >> 4, h2 = (e >> 3) & 1, ii = e & 7;
                Kp[(size_t)kb * 2048 + c * 512 + (h2 * 32 + jq) * 8 + ii] =
                    __float2bfloat16(ka[i]);
            }
            if (e < 32) {  // Vp: thread e holds gated[key=j][vdim=e]
                const int h = jq >> 4, h3 = (jq >> 3) & 1, ii = jq & 7;
                Vp[(size_t)kb * 1024 + h * 512 + (h3 * 32 + e) * 8 + ii] =
                    __float2bfloat16(g);
            }
        }
    }
}

// -------------------------------------------------------------- attn ------
// grid = (n_map/128) * ks. Block: qb = bid>>kslog (4 q-tiles = 128 q-rows),
// slice = bid & (ks-1). Wave w owns q-tile qb*4+w; all 4 waves scan the same
// key slab; same-slice blocks land on the same XCD (bid%8 == slice%8) so the
// slab stays L2-resident. Swapped QK^T (Q pre-scaled by IT), O^T orientation,
// no-max softmax, packed-coalesced K/V, 2-deep ping-pong prefetch, barrier
// every 4 kb. Per-wave partials -> oP (bf16) / lP (f32).
#define WAVES 4
__global__ __launch_bounds__(64 * WAVES, 4) void attn_partial(
    const __hip_bfloat16* __restrict__ qbf, const __hip_bfloat16* __restrict__ Kp,
    const __hip_bfloat16* __restrict__ Vp,
    __hip_bfloat16* __restrict__ oP, float* __restrict__ lP,
    int n_obs, int n_map, int kslog)
{
    const int tid  = threadIdx.x;
    const int w    = tid >> 6;
    const int lane = tid & 63;
    const int ql   = lane & 31;
    const int hi   = lane >> 5;
    const int ks   = 1 << kslog;
    const int qb   = blockIdx.x >> kslog;
    const int slice= blockIdx.x & (ks - 1);
    const int tileT= qb * WAVES + w;           // global q-tile index
    const int q    = tileT * 32 + ql;

    // Q fragments: qf[c][j] = (IT*Q)[q][16c + 8hi + j]
    bf16x8 qf[4];
    {
        const __hip_bfloat16* qrow = qbf + (size_t)q * 64 + 8 * hi;
        #pragma unroll
        for (int c = 0; c < 4; ++c)
            qf[c] = *reinterpret_cast<const bf16x8*>(qrow + c * 16);
    }

    float lsumA = 0.0f, lsumB = 0.0f;
    f32x16 o = {};

    const int nkb      = (n_obs >> kslog) >> 5;   // key-blocks per slice
    const int kb_begin = slice * nkb;
    const int kb_end   = kb_begin + nkb;
    const __hip_bfloat16* Kw = Kp + (size_t)lane * 8;
    const __hip_bfloat16* Vw = Vp + (size_t)lane * 8;

    auto loadKV = [&](int kb, bf16x8 (&kf)[4], bf16x8 (&vf)[2]) {
        const __hip_bfloat16* kbp = Kw + (size_t)kb * 2048;
        #pragma unroll
        for (int c = 0; c < 4; ++c)
            kf[c] = *reinterpret_cast<const bf16x8*>(kbp + c * 512);
        const __hip_bfloat16* vbp = Vw + (size_t)kb * 1024;
        vf[0] = *reinterpret_cast<const bf16x8*>(vbp);
        vf[1] = *reinterpret_cast<const bf16x8*>(vbp + 512);
    };

    auto body = [&](const bf16x8 (&kf)[4], const bf16x8 (&vf)[2]) {
        // ---- QK^T (swapped): S^T[key][q], pre-scaled by IT ----
        f32x16 s = {};
        #pragma unroll
        for (int c = 0; c < 4; ++c)
            s = __builtin_amdgcn_mfma_f32_32x32x16_bf16(kf[c], qf[c], s, 0, 0, 0);
        // ---- p = 2^s (args bounded; raw HW exp) ----
        float p[16];
        #pragma unroll
        for (int r = 0; r < 16; ++r) p[r] = __builtin_amdgcn_exp2f(s[r]);
        #pragma unroll
        for (int r = 0; r < 8; ++r) { lsumA += p[r]; lsumB += p[r + 8]; }
        // ---- P -> bf16 PV fragments (cvt_pk + permlane32_swap) ----
        union { u32 u[4]; bf16x8 v; } pb0, pb1;
        {
            u32 x0 = cvt_pk_bf16(p[0], p[1]);
            u32 x1 = cvt_pk_bf16(p[2], p[3]);
            u32 y0 = cvt_pk_bf16(p[4], p[5]);
            u32 y1 = cvt_pk_bf16(p[6], p[7]);
            permswap32(x0, y0);
            permswap32(x1, y1);
            pb0.u[0] = x0; pb0.u[1] = x1; pb0.u[2] = y0; pb0.u[3] = y1;
        }
        {
            u32 x0 = cvt_pk_bf16(p[8],  p[9]);
            u32 x1 = cvt_pk_bf16(p[10], p[11]);
            u32 y0 = cvt_pk_bf16(p[12], p[13]);
            u32 y1 = cvt_pk_bf16(p[14], p[15]);
            permswap32(x0, y0);
            permswap32(x1, y1);
            pb1.u[0] = x0; pb1.u[1] = x1; pb1.u[2] = y0; pb1.u[3] = y1;
        }
        // ---- PV: O^T += V^T x P^T ----
        o = __builtin_amdgcn_mfma_f32_32x32x16_bf16(vf[0], pb0.v, o, 0, 0, 0);
        o = __builtin_amdgcn_mfma_f32_32x32x16_bf16(vf[1], pb1.v, o, 0, 0, 0);
    };

    // ---- ping-pong prefetched main loop; barrier every 4 kb bounds wave
    // drift so the 4 waves share each other's L1-resident key blocks ----
    bf16x8 kA[4], kB[4], vA[2], vB[2];
    loadKV(kb_begin, kA, vA);
    int it = 0;
    for (int kb = kb_begin; kb < kb_end; kb += 2, ++it) {
        loadKV(kb + 1, kB, vB);
        body(kA, vA);
        const int kn = (kb + 2 < kb_end) ? kb + 2 : kb_begin;
        loadKV(kn, kA, vA);
        body(kB, vB);
        if ((it & 1) == 1) __syncthreads();   // re-converge waves
    }

    // ---- per-wave partials -> global ----
    float lsum = lsumA + lsumB;
    lsum += __shfl_xor(lsum, 32);   // combine key-halves
    if (hi == 0) lP[(size_t)slice * n_map + tileT * 32 + ql] = lsum;
    __hip_bfloat16* ob = oP + ((size_t)slice * (n_map >> 5) + tileT) * 1024;
    #pragma unroll
    for (int r = 0; r < 16; ++r) {
        const int vr = (r & 3) + 8 * (r >> 2) + 4 * hi;
        ob[vr * 32 + ql] = __float2bfloat16(o[r]);
    }
}

// --------------------------------------------------------- combine_epi ----
// grid = ntiles; 256 thr = 4 waves; sums ks slices, then Wo/residual/LN.
__global__ __launch_bounds__(256) void combine_epi(
    const __hip_bfloat16* __restrict__ oP, const float* __restrict__ lP,
    const float* __restrict__ self_score, const float* __restrict__ gated_map,
    const float* __restrict__ map_code, const float* __restrict__ Wo,
    const float* __restrict__ bo, const float* __restrict__ gamma,
    const float* __restrict__ beta, float* __restrict__ out,
    int n_map, int ks)
{
    const int tid  = threadIdx.x;
    const int w    = tid >> 6;
    const int lane = tid & 63;
    const int T    = blockIdx.x;
    const int q0   = T * 32;
    const int ntiles = n_map >> 5;

    __shared__ float aggT[32][33];
    __shared__ float invS[32];
    __shared__ float psS[32];

    if (tid < 32) {
        const float ps = __builtin_amdgcn_exp2f(self_score[q0 + tid] * IT);
        psS[tid] = ps;
        float l = ps;
        for (int s = 0; s < ks; ++s)
            l += lP[(size_t)s * n_map + q0 + tid];
        invS[tid] = 1.0f / l;
    }
    __syncthreads();

    #pragma unroll
    for (int t = tid; t < 1024; t += 256) {
        const int v  = t >> 5;
        const int qq = t & 31;
        float a = psS[qq] * gated_map[(size_t)(q0 + qq) * 32 + v];
        for (int s = 0; s < ks; ++s)
            a += __bfloat162float(oP[((size_t)s * ntiles + T) * 1024 + t]);
        aggT[v][qq] = a;
    }
    __syncthreads();

    float wo[32];
    #pragma unroll
    for (int vv = 0; vv < 32; ++vv) wo[vv] = Wo[vv * 64 + lane];
    const float bo_e = bo[lane], ga = gamma[lane], be = beta[lane];

    #pragma unroll
    for (int i = 0; i < 8; ++i) {
        const int qq = w * 8 + i;
        float dot = 0.0f;
        #pragma unroll
        for (int vv = 0; vv < 32; ++vv)
            dot = fmaf(aggT[vv][qq], wo[vv], dot); // LDS broadcast reads
        float acc = dot * invS[qq] + bo_e + map_code[(size_t)(q0 + qq) * 64 + lane];
        float mu = acc;
        #pragma unroll
        for (int off = 32; off; off >>= 1) mu += __shfl_xor(mu, off);
        mu *= (1.0f / 64.0f);
        const float dc = acc - mu;
        float var = dc * dc;
        #pragma unroll
        for (int off = 32; off; off >>= 1) var += __shfl_xor(var, off);
        var *= (1.0f / 64.0f);
        out[(size_t)(q0 + qq) * 64 + lane] =
            dc * rsqrtf(var + 1e-6f) * ga + be;
    }
}

// -------------------------------------------------------------- launch ----
extern "C" void kernel_launch(void* const* d_in, const int* in_sizes, int n_in,
                              void* d_out, int out_size, void* d_ws, size_t ws_size,
                              hipStream_t stream) {
    const float* map_code = (const float*)d_in[0];
    const float* obs_code = (const float*)d_in[1];
    const float* Wq  = (const float*)d_in[2];
    const float* Wk  = (const float*)d_in[3];
    const float* Wv  = (const float*)d_in[4];
    const float* Wo  = (const float*)d_in[5];
    const float* bo  = (const float*)d_in[6];
    const float* gam = (const float*)d_in[7];
    const float* bet = (const float*)d_in[8];
    const int n_map = in_sizes[0] / 64;   // 16384
    const int n_obs = in_sizes[1] / 64;   // 8192
    const int ntiles = n_map / 32;        // 512

    char* ws = (char*)d_ws;
    __hip_bfloat16* qbf = (__hip_bfloat16*)ws; ws += (size_t)n_map * 64 * 2;
    __hip_bfloat16* Kp  = (__hip_bfloat16*)ws; ws += (size_t)n_obs * 64 * 2;
    __hip_bfloat16* Vp  = (__hip_bfloat16*)ws; ws += (size_t)n_obs * 32 * 2;
    float* self_score   = (float*)ws;          ws += (size_t)n_map * 4;
    float* gated_map    = (float*)ws;          ws += (size_t)n_map * 32 * 4;
    const size_t base   = (size_t)(ws - (char*)d_ws);
    // per-slice partial cost: oP (n_map*32 bf16) + lP (n_map f32)
    const size_t per_slice = (size_t)n_map * 32 * 2 + (size_t)n_map * 4;
    int kslog = 4;   // ks=16 -> grid 2048 = 8 blocks/CU (occupancy 100%)
    while (kslog > 0 && base + ((size_t)1 << kslog) * per_slice > ws_size)
        --kslog;
    const int ks = 1 << kslog;
    __hip_bfloat16* oP = (__hip_bfloat16*)ws; ws += (size_t)ks * n_map * 32 * 2;
    float* lP = (float*)ws;  // ks * n_map * 4

    const int total = n_map + n_obs;
    prep_kernel<<<(total + 31) / 32, 256, 0, stream>>>(
        map_code, obs_code, Wq, Wk, Wv, qbf, Kp, Vp, self_score, gated_map,
        n_map, n_obs);
    attn_partial<<<(n_map / 128) * ks, 64 * WAVES, 0, stream>>>(
        qbf, Kp, Vp, oP, lP, n_obs, n_map, kslog);
    combine_epi<<<ntiles, 256, 0, stream>>>(
        oP, lP, self_score, gated_map, map_code, Wo, bo, gam, bet,
        (float*)d_out, n_map, ks);
}

// Round 11
// 70.605 us; speedup vs baseline: 1.1786x; 1.1786x over previous
//
#include <hip/hip_runtime.h>
#include <hip/hip_bf16.h>

// Fused map-obs attention (Attention_5815385719367), MI355X/gfx950.
// R11: attn was stuck at ~42us across R7-R10 regardless of grid/ks ->
// register-capped at 4 waves/SIMD AND every wave redundantly streaming the
// same 6KB key-block (786MB of L2 requests). Fix: LDS-stage K/V once per
// BLOCK (reg-staged T14 pattern: global->reg 2 rounds ahead, ds_write into
// 2x12KB double buffer, 1 barrier/round), all 4 waves ds_read fragments.
// L2 read traffic /4, VMEM latency off the critical path. ks=8 (grid 1024 =
// 4 blocks/CU x 4 waves = reg-cap occupancy).
//
// ws layout (~14 MB):
//   qbf  [n_map][64] bf16 (pre-scaled by IT)
//   Kp   [n_obs/32][4][64][8] bf16    (packed K fragments, 4KB/kb)
//   Vp   [n_obs/32][2][64][8] bf16    (packed V^T fragments, 2KB/kb)
//   self_score[n_map] f32, gated_map[n_map][32] f32
//   oP [ks][ntiles][32][32] bf16,  lP [ks][n_map] f32

typedef float f32x16 __attribute__((ext_vector_type(16)));
typedef short bf16x8 __attribute__((ext_vector_type(8)));
typedef unsigned int u32;

__device__ __forceinline__ u32 cvt_pk_bf16(float lo, float hi) {
    u32 r;
    asm("v_cvt_pk_bf16_f32 %0, %1, %2" : "=v"(r) : "v"(lo), "v"(hi));
    return r;
}
__device__ __forceinline__ void permswap32(u32& a, u32& b) {
    asm("v_permlane32_swap_b32 %0, %1" : "+v"(a), "+v"(b));
}

#define IT 0.18033688011112042f  // log2(e)/TEMPERATURE, T=8
#define LOG2E 1.44269504089f

// ---------------------------------------------------------------- prep ----
// 256 thr = 4 waves; wave handles 8 rows (32 rows/block), d-loop outer.
__global__ __launch_bounds__(256) void prep_kernel(
    const float* __restrict__ map_code, const float* __restrict__ obs_code,
    const float* __restrict__ Wq, const float* __restrict__ Wk,
    const float* __restrict__ Wv,
    __hip_bfloat16* __restrict__ qbf, __hip_bfloat16* __restrict__ Kp,
    __hip_bfloat16* __restrict__ Vp, float* __restrict__ self_score,
    float* __restrict__ gated_map, int n_map, int n_obs)
{
    __shared__ float xs[32 * 64];
    const int t = threadIdx.x;
    const int w = t >> 6;
    const int e = t & 63;
    const int r0 = blockIdx.x * 32;
    const int total = n_map + n_obs;

    // stage 32 rows of concat(map, obs), coalesced
    #pragma unroll
    for (int i = 0; i < 8; ++i) {
        const int idx = i * 256 + t;
        const int gr = r0 + (idx >> 6);
        const int col = idx & 63;
        float val = 0.0f;
        if (gr < n_map)      val = map_code[(size_t)gr * 64 + col];
        else if (gr < total) val = obs_code[(size_t)(gr - n_map) * 64 + col];
        xs[idx] = val;
    }
    __syncthreads();

    float qa[8] = {}, ka[8] = {}, va[8] = {};
    const float* xw = xs + (w * 8) * 64;
    #pragma unroll 4
    for (int d = 0; d < 64; ++d) {
        const float wq = Wq[d * 64 + e];
        const float wk = Wk[d * 64 + e];
        const float wv = Wv[d * 64 + e];
        #pragma unroll
        for (int i = 0; i < 8; ++i) {
            const float x = xw[i * 64 + d];   // LDS broadcast
            qa[i] = fmaf(x, wq, qa[i]);
            ka[i] = fmaf(x, wk, ka[i]);
            va[i] = fmaf(x, wv, va[i]);
        }
    }

    #pragma unroll
    for (int i = 0; i < 8; ++i) {
        const int r = r0 + w * 8 + i;
        if (r >= total) break;
        const bool is_map = r < n_map;
        // GLU: lanes 0..31 hold a=v[e], need b=v[e+32]
        const float vother = __shfl_xor(va[i], 32);
        const float sig = 1.0f / (1.0f + __builtin_amdgcn_exp2f(-vother * LOG2E));
        const float g = va[i] * sig; // valid for lanes e < 32

        if (is_map) {
            qbf[(size_t)r * 64 + e] = __float2bfloat16(qa[i] * IT);
            float qk = qa[i] * ka[i];
            #pragma unroll
            for (int off = 32; off; off >>= 1) qk += __shfl_xor(qk, off);
            if (e == 0) self_score[r] = qk;
            if (e < 32) gated_map[(size_t)r * 32 + e] = g;
        } else {
            const int j  = r - n_map;          // key index
            const int kb = j >> 5, jq = j & 31;
            {   // Kp: thread e holds K[j][d=e]
                const int c = e >> 4, h2 = (e >> 3) & 1, ii = e & 7;
                Kp[(size_t)kb * 2048 + c * 512 + (h2 * 32 + jq) * 8 + ii] =
                    __float2bfloat16(ka[i]);
            }
            if (e < 32) {  // Vp: thread e holds gated[key=j][vdim=e]
                const int h = jq >> 4, h3 = (jq >> 3) & 1, ii = jq & 7;
                Vp[(size_t)kb * 1024 + h * 512 + (h3 * 32 + e) * 8 + ii] =
                    __float2bfloat16(g);
            }
        }
    }
}

// -------------------------------------------------------------- attn ------
// grid = (n_map/128) * ks. Block: qb = bid>>kslog (4 q-tiles = 128 q-rows),
// slice = bid & (ks-1). Wave w owns q-tile qb*4+w. K/V staged in LDS once
// per block, double-buffered in 2-kb rounds:
//   round r: barrier; ds_read sub0; ds_write next pair (from regs);
//            global-load pair r+2 -> regs; body0; ds_read sub1; body1.
// Swapped QK^T (Q pre-scaled by IT), O^T orientation, no-max softmax.
#define WAVES 4
__global__ __launch_bounds__(64 * WAVES, 4) void attn_partial(
    const __hip_bfloat16* __restrict__ qbf, const __hip_bfloat16* __restrict__ Kp,
    const __hip_bfloat16* __restrict__ Vp,
    __hip_bfloat16* __restrict__ oP, float* __restrict__ lP,
    int n_obs, int n_map, int kslog)
{
    const int tid  = threadIdx.x;
    const int w    = tid >> 6;
    const int lane = tid & 63;
    const int ql   = lane & 31;
    const int hi   = lane >> 5;
    const int ks   = 1 << kslog;
    const int qb   = blockIdx.x >> kslog;
    const int slice= blockIdx.x & (ks - 1);
    const int tileT= qb * WAVES + w;           // global q-tile index
    const int q    = tileT * 32 + ql;

    // double-buffered K/V pair staging: [2] x (K 8KB | V 4KB)
    __shared__ __align__(16) char kv[2][12288];

    // Q fragments: qf[c][j] = (IT*Q)[q][16c + 8hi + j]
    bf16x8 qf[4];
    {
        const __hip_bfloat16* qrow = qbf + (size_t)q * 64 + 8 * hi;
        #pragma unroll
        for (int c = 0; c < 4; ++c)
            qf[c] = *reinterpret_cast<const bf16x8*>(qrow + c * 16);
    }

    float lsumA = 0.0f, lsumB = 0.0f;
    f32x16 o = {};

    const int nkb      = (n_obs >> kslog) >> 5;   // key-blocks per slice
    const int kb_begin = slice * nkb;
    const int npairs   = nkb >> 1;
    const char* Kb = (const char*)Kp;
    const char* Vb = (const char*)Vp;

    uint4 gK0, gK1, gV;
    auto gloadPair = [&](int kb0) {   // stage kbs (kb0, kb0+1) -> regs
        const char* ksrc = Kb + (size_t)kb0 * 4096 + tid * 32;
        gK0 = *reinterpret_cast<const uint4*>(ksrc);
        gK1 = *reinterpret_cast<const uint4*>(ksrc + 16);
        gV  = *reinterpret_cast<const uint4*>(Vb + (size_t)kb0 * 2048 + tid * 16);
    };
    auto swritePair = [&](char* buf) {
        *reinterpret_cast<uint4*>(buf + tid * 32)        = gK0;
        *reinterpret_cast<uint4*>(buf + tid * 32 + 16)   = gK1;
        *reinterpret_cast<uint4*>(buf + 8192 + tid * 16) = gV;
    };
    auto readsub = [&](const char* buf, int j, bf16x8 (&kf)[4], bf16x8 (&vf)[2]) {
        const char* kbp = buf + j * 4096 + lane * 16;
        #pragma unroll
        for (int c = 0; c < 4; ++c)
            kf[c] = *reinterpret_cast<const bf16x8*>(kbp + c * 1024);
        const char* vbp = buf + 8192 + j * 2048 + lane * 16;
        vf[0] = *reinterpret_cast<const bf16x8*>(vbp);
        vf[1] = *reinterpret_cast<const bf16x8*>(vbp + 1024);
    };

    auto body = [&](const bf16x8 (&kf)[4], const bf16x8 (&vf)[2]) {
        // ---- QK^T (swapped): S^T[key][q], pre-scaled by IT ----
        f32x16 s = {};
        #pragma unroll
        for (int c = 0; c < 4; ++c)
            s = __builtin_amdgcn_mfma_f32_32x32x16_bf16(kf[c], qf[c], s, 0, 0, 0);
        // ---- p = 2^s (args bounded; raw HW exp) ----
        float p[16];
        #pragma unroll
        for (int r = 0; r < 16; ++r) p[r] = __builtin_amdgcn_exp2f(s[r]);
        #pragma unroll
        for (int r = 0; r < 8; ++r) { lsumA += p[r]; lsumB += p[r + 8]; }
        // ---- P -> bf16 PV fragments (cvt_pk + permlane32_swap) ----
        union { u32 u[4]; bf16x8 v; } pb0, pb1;
        {
            u32 x0 = cvt_pk_bf16(p[0], p[1]);
            u32 x1 = cvt_pk_bf16(p[2], p[3]);
            u32 y0 = cvt_pk_bf16(p[4], p[5]);
            u32 y1 = cvt_pk_bf16(p[6], p[7]);
            permswap32(x0, y0);
            permswap32(x1, y1);
            pb0.u[0] = x0; pb0.u[1] = x1; pb0.u[2] = y0; pb0.u[3] = y1;
        }
        {
            u32 x0 = cvt_pk_bf16(p[8],  p[9]);
            u32 x1 = cvt_pk_bf16(p[10], p[11]);
            u32 y0 = cvt_pk_bf16(p[12], p[13]);
            u32 y1 = cvt_pk_bf16(p[14], p[15]);
            permswap32(x0, y0);
            permswap32(x1, y1);
            pb1.u[0] = x0; pb1.u[1] = x1; pb1.u[2] = y0; pb1.u[3] = y1;
        }
        // ---- PV: O^T += V^T x P^T ----
        o = __builtin_amdgcn_mfma_f32_32x32x16_bf16(vf[0], pb0.v, o, 0, 0, 0);
        o = __builtin_amdgcn_mfma_f32_32x32x16_bf16(vf[1], pb1.v, o, 0, 0, 0);
    };

    // ---- prologue: pair 0 into buf0; pair 1 into regs ----
    gloadPair(kb_begin);
    swritePair(kv[0]);
    gloadPair(npairs > 1 ? kb_begin + 2 : kb_begin);

    int cur = 0;
    bf16x8 kf[4], vf[2];
    for (int r = 0; r < npairs; ++r) {
        __syncthreads();                       // buf[cur] ready for all
        readsub(kv[cur], 0, kf, vf);
        swritePair(kv[cur ^ 1]);               // pair r+1 -> other buffer
        gloadPair(r + 2 < npairs ? kb_begin + 2 * (r + 2) : kb_begin);
        body(kf, vf);
        readsub(kv[cur], 1, kf, vf);
        body(kf, vf);
        cur ^= 1;
    }

    // ---- per-wave partials -> global ----
    float lsum = lsumA + lsumB;
    lsum += __shfl_xor(lsum, 32);   // combine key-halves
    if (hi == 0) lP[(size_t)slice * n_map + tileT * 32 + ql] = lsum;
    __hip_bfloat16* ob = oP + ((size_t)slice * (n_map >> 5) + tileT) * 1024;
    #pragma unroll
    for (int r = 0; r < 16; ++r) {
        const int vr = (r & 3) + 8 * (r >> 2) + 4 * hi;
        ob[vr * 32 + ql] = __float2bfloat16(o[r]);
    }
}

// --------------------------------------------------------- combine_epi ----
// grid = ntiles; 256 thr = 4 waves; sums ks slices, then Wo/residual/LN.
__global__ __launch_bounds__(256) void combine_epi(
    const __hip_bfloat16* __restrict__ oP, const float* __restrict__ lP,
    const float* __restrict__ self_score, const float* __restrict__ gated_map,
    const float* __restrict__ map_code, const float* __restrict__ Wo,
    const float* __restrict__ bo, const float* __restrict__ gamma,
    const float* __restrict__ beta, float* __restrict__ out,
    int n_map, int ks)
{
    const int tid  = threadIdx.x;
    const int w    = tid >> 6;
    const int lane = tid & 63;
    const int T    = blockIdx.x;
    const int q0   = T * 32;
    const int ntiles = n_map >> 5;

    __shared__ float aggT[32][33];
    __shared__ float invS[32];
    __shared__ float psS[32];

    if (tid < 32) {
        const float ps = __builtin_amdgcn_exp2f(self_score[q0 + tid] * IT);
        psS[tid] = ps;
        float l = ps;
        for (int s = 0; s < ks; ++s)
            l += lP[(size_t)s * n_map + q0 + tid];
        invS[tid] = 1.0f / l;
    }
    __syncthreads();

    #pragma unroll
    for (int t = tid; t < 1024; t += 256) {
        const int v  = t >> 5;
        const int qq = t & 31;
        float a = psS[qq] * gated_map[(size_t)(q0 + qq) * 32 + v];
        for (int s = 0; s < ks; ++s)
            a += __bfloat162float(oP[((size_t)s * ntiles + T) * 1024 + t]);
        aggT[v][qq] = a;
    }
    __syncthreads();

    float wo[32];
    #pragma unroll
    for (int vv = 0; vv < 32; ++vv) wo[vv] = Wo[vv * 64 + lane];
    const float bo_e = bo[lane], ga = gamma[lane], be = beta[lane];

    #pragma unroll
    for (int i = 0; i < 8; ++i) {
        const int qq = w * 8 + i;
        float dot = 0.0f;
        #pragma unroll
        for (int vv = 0; vv < 32; ++vv)
            dot = fmaf(aggT[vv][qq], wo[vv], dot); // LDS broadcast reads
        float acc = dot * invS[qq] + bo_e + map_code[(size_t)(q0 + qq) * 64 + lane];
        float mu = acc;
        #pragma unroll
        for (int off = 32; off; off >>= 1) mu += __shfl_xor(mu, off);
        mu *= (1.0f / 64.0f);
        const float dc = acc - mu;
        float var = dc * dc;
        #pragma unroll
        for (int off = 32; off; off >>= 1) var += __shfl_xor(var, off);
        var *= (1.0f / 64.0f);
        out[(size_t)(q0 + qq) * 64 + lane] =
            dc * rsqrtf(var + 1e-6f) * ga + be;
    }
}

// -------------------------------------------------------------- launch ----
extern "C" void kernel_launch(void* const* d_in, const int* in_sizes, int n_in,
                              void* d_out, int out_size, void* d_ws, size_t ws_size,
                              hipStream_t stream) {
    const float* map_code = (const float*)d_in[0];
    const float* obs_code = (const float*)d_in[1];
    const float* Wq  = (const float*)d_in[2];
    const float* Wk  = (const float*)d_in[3];
    const float* Wv  = (const float*)d_in[4];
    const float* Wo  = (const float*)d_in[5];
    const float* bo  = (const float*)d_in[6];
    const float* gam = (const float*)d_in[7];
    const float* bet = (const float*)d_in[8];
    const int n_map = in_sizes[0] / 64;   // 16384
    const int n_obs = in_sizes[1] / 64;   // 8192
    const int ntiles = n_map / 32;        // 512

    char* ws = (char*)d_ws;
    __hip_bfloat16* qbf = (__hip_bfloat16*)ws; ws += (size_t)n_map * 64 * 2;
    __hip_bfloat16* Kp  = (__hip_bfloat16*)ws; ws += (size_t)n_obs * 64 * 2;
    __hip_bfloat16* Vp  = (__hip_bfloat16*)ws; ws += (size_t)n_obs * 32 * 2;
    float* self_score   = (float*)ws;          ws += (size_t)n_map * 4;
    float* gated_map    = (float*)ws;          ws += (size_t)n_map * 32 * 4;
    const size_t base   = (size_t)(ws - (char*)d_ws);
    // per-slice partial cost: oP (n_map*32 bf16) + lP (n_map f32)
    const size_t per_slice = (size_t)n_map * 32 * 2 + (size_t)n_map * 4;
    int kslog = 3;   // ks=8 -> grid 1024 = 4 blocks/CU (reg-cap occupancy)
    while (kslog > 0 && base + ((size_t)1 << kslog) * per_slice > ws_size)
        --kslog;
    const int ks = 1 << kslog;
    __hip_bfloat16* oP = (__hip_bfloat16*)ws; ws += (size_t)ks * n_map * 32 * 2;
    float* lP = (float*)ws;  // ks * n_map * 4

    const int total = n_map + n_obs;
    prep_kernel<<<(total + 31) / 32, 256, 0, stream>>>(
        map_code, obs_code, Wq, Wk, Wv, qbf, Kp, Vp, self_score, gated_map,
        n_map, n_obs);
    attn_partial<<<(n_map / 128) * ks, 64 * WAVES, 0, stream>>>(
        qbf, Kp, Vp, oP, lP, n_obs, n_map, kslog);
    combine_epi<<<ntiles, 256, 0, stream>>>(
        oP, lP, self_score, gated_map, map_code, Wo, bo, gam, bet,
        (float*)d_out, n_map, ks);
}